// Round 9
// baseline (341.782 us; speedup 1.0000x reference)
//
#include <hip/hip_runtime.h>
#include <math.h>

constexpr int B_ = 16, E_ = 256, NC_ = 8, Q_ = 40, H_ = 64, W_ = 64, HW_ = 4096;
constexpr int NH_ = 8, HD_ = 32, OF_ = 64;
constexpr int KP1_ = 320;          // padded K for gemm1 (E+NC=264 -> 320)
constexpr int NPART_ = 16;         // attention partials per (b,head): 4 chunks x 4 waves
constexpr int KVS_ = 512;          // kv buffer row stride (k cols 0..255, v cols 256..511)

typedef __attribute__((ext_vector_type(8))) unsigned short us8;
typedef __attribute__((ext_vector_type(8))) short s8b;     // bf16 MFMA frag
typedef __attribute__((ext_vector_type(4))) float f32x4;

__device__ __forceinline__ float gelu_f(float x) {
  return 0.5f * x * (1.0f + erff(x * 0.70710678118654752f));
}
__device__ __forceinline__ float bf2f(unsigned short u) {
  return __uint_as_float(((unsigned int)u) << 16);
}
__device__ __forceinline__ unsigned short f2bf(float f) {
  unsigned int u = __float_as_uint(f);
  u = u + 0x7fff + ((u >> 16) & 1);  // RNE
  return (unsigned short)(u >> 16);
}
// async global->LDS 16B; LDS dest linear in lane (wave base + lane*16)
__device__ __forceinline__ void gl_lds16(const unsigned short* g, unsigned short* l) {
  __builtin_amdgcn_global_load_lds(
      (const __attribute__((address_space(1))) unsigned int*)g,
      (__attribute__((address_space(3))) unsigned int*)l, 16, 0, 0);
}

// ---------- q branch (DO_LN=true) / final projection (DO_LN=false) ----------
template<bool DO_LN>
__global__ __launch_bounds__(256)
void row_gemm256(const float* __restrict__ X, const float* __restrict__ g,
                 const float* __restrict__ bt, const float* __restrict__ Wm,
                 const float* __restrict__ bias, float* __restrict__ Y) {
  const int row = blockIdx.x;
  const int t = threadIdx.x;
  __shared__ float xs[E_];
  float x = X[(size_t)row * E_ + t];
  if constexpr (DO_LN) {
    __shared__ float rs[4], rs2[4];
    __shared__ float smean, srstd;
    float s = x, s2 = x * x;
    #pragma unroll
    for (int o = 32; o > 0; o >>= 1) { s += __shfl_down(s, o, 64); s2 += __shfl_down(s2, o, 64); }
    if ((t & 63) == 0) { rs[t >> 6] = s; rs2[t >> 6] = s2; }
    __syncthreads();
    if (t == 0) {
      float S = rs[0] + rs[1] + rs[2] + rs[3];
      float S2 = rs2[0] + rs2[1] + rs2[2] + rs2[3];
      float m = S * (1.0f / E_);
      smean = m;
      srstd = rsqrtf(S2 * (1.0f / E_) - m * m + 1e-5f);
    }
    __syncthreads();
    x = (x - smean) * srstd * g[t] + bt[t];
  }
  xs[t] = x;
  __syncthreads();
  float acc = bias[t];
  #pragma unroll 8
  for (int c = 0; c < E_; ++c) acc += xs[c] * Wm[(size_t)c * E_ + t];
  Y[(size_t)row * E_ + t] = acc;
}

// ---------- weight prep: transpose+cast; kv weights stacked [512][256] ----------
__global__ __launch_bounds__(256)
void wprep(const float* __restrict__ w1, const float* __restrict__ w2,
           const float* __restrict__ wk, const float* __restrict__ wv,
           const float* __restrict__ kb, const float* __restrict__ vb,
           unsigned short* __restrict__ o1, unsigned short* __restrict__ o2,
           unsigned short* __restrict__ okv, float* __restrict__ kvbias) {
  const int n = threadIdx.x;
  const int k = blockIdx.x;
  const int which = blockIdx.y;
  if (which == 0) {
    float v = (k < 264) ? w1[(size_t)k * E_ + n] : 0.f;
    o1[(size_t)n * KP1_ + k] = f2bf(v);
  } else if (k < 256) {
    if (which == 1) {
      o2[(size_t)n * 256 + k] = f2bf(w2[(size_t)k * E_ + n]);
    } else if (which == 2) {
      okv[(size_t)n * 256 + k] = f2bf(wk[(size_t)k * E_ + n]);
      if (k == 0) kvbias[n] = kb[n];
    } else {
      okv[(size_t)(256 + n) * 256 + k] = f2bf(wv[(size_t)k * E_ + n]);
      if (k == 0) kvbias[256 + n] = vb[n];
    }
  }
}

// ---------- xcatT: bf16 [B*HW][KP1] from channel-major img/msk ----------
__global__ __launch_bounds__(256)
void xcat_t(const float* __restrict__ img, const float* __restrict__ msk,
            unsigned short* __restrict__ out) {
  __shared__ float tile[64][65];
  const int t = threadIdx.x;
  const int p0 = blockIdx.x * 64;
  const int k0 = blockIdx.y * 64;
  const int b = blockIdx.z;
  const int kk = t >> 6, pl = t & 63;
  #pragma unroll
  for (int ki = 0; ki < 16; ++ki) {
    const int k = k0 + kk * 16 + ki;
    float v;
    if (k < 256)      v = img[((size_t)b * E_ + k) * HW_ + p0 + pl];
    else if (k < 264) v = msk[((size_t)b * NC_ + (k - 256)) * HW_ + p0 + pl];
    else              v = 0.f;
    tile[pl][kk * 16 + ki] = v;
  }
  __syncthreads();
  const int pr = t >> 2, ch = t & 3;
  unsigned short st[16];
  #pragma unroll
  for (int i = 0; i < 16; ++i) st[i] = f2bf(tile[pr][ch * 16 + i]);
  unsigned short* dst = out + ((size_t)b * HW_ + p0 + pr) * KP1_ + k0 + ch * 16;
  *(us8*)dst = *(const us8*)&st[0];
  *(us8*)(dst + 8) = *(const us8*)&st[8];
}

// ---------- bsgemm: B-stationary, barrier-free K-loop ----------
// C[M,OSTR slice] = A[M,KP] @ Wt[n0+128 rows][KP]^T + bias.
// 512 thr (8 waves); block = 512 rows x 128 cols; wave = 64 rows x 128 cols.
// B panel staged ONCE in LDS (XOR-swizzled source), then zero barriers over K.
#define LDA_BS(dst, kk)                                                      \
  {                                                                          \
    _Pragma("unroll")                                                        \
    for (int mf = 0; mf < 4; ++mf)                                           \
      dst[mf] = *(const s8b*)(Aw + (size_t)(mf * 16) * KP + (kk) * 32);      \
  }
#define STEP_BS(af, kk)                                                      \
  {                                                                          \
    _Pragma("unroll")                                                        \
    for (int nf = 0; nf < 8; ++nf) {                                         \
      const int brow = nf * 16 + c;                                          \
      const int sl = (kk) * 4 + g;                                           \
      const int ph = (sl & ~7) | ((sl & 7) ^ (brow & 7));                    \
      const s8b bf = *(const s8b*)&lds[brow * (KP) + ph * 8];                \
      _Pragma("unroll")                                                      \
      for (int mf = 0; mf < 4; ++mf)                                         \
        acc[mf][nf] = __builtin_amdgcn_mfma_f32_16x16x32_bf16(af[mf], bf, acc[mf][nf], 0, 0, 0); \
    }                                                                        \
  }
template<int EPI, int KP, int OSTR>
__global__ __launch_bounds__(512, 2)
void bsgemm(const unsigned short* __restrict__ A, const unsigned short* __restrict__ Wt,
            const float* __restrict__ bias, unsigned short* __restrict__ out) {
  constexpr int NKS = KP / 32;                    // 8 or 10 (even)
  constexpr int ROWSLOTS = KP / 8;
  constexpr int BSLOTS = 128 * ROWSLOTS;
  __shared__ __align__(16) unsigned short lds[(128 * KP) > 32768 ? (128 * KP) : 32768];
  const int t = threadIdx.x;
  const int m0 = blockIdx.x * 512;
  const int n0 = blockIdx.y * 128;
  const int w = t >> 6, lane = t & 63;
  const int c = lane & 15, g = lane >> 4;
  const int wrow = w * 64;

  // stage B panel once (source-slot swizzled so reads are conflict-free)
  #pragma unroll
  for (int i = 0; i < BSLOTS / 512; ++i) {
    const int f = i * 512 + t;
    const int row = f / ROWSLOTS, s = f % ROWSLOTS;
    const int su = (s & ~7) | ((s & 7) ^ (row & 7));
    gl_lds16(Wt + (size_t)(n0 + row) * KP + su * 8, lds + f * 8);
  }
  __syncthreads();

  f32x4 acc[4][8];
  #pragma unroll
  for (int i = 0; i < 4; ++i)
    #pragma unroll
    for (int j = 0; j < 8; ++j) acc[i][j] = (f32x4){0.f, 0.f, 0.f, 0.f};

  const unsigned short* Aw = A + (size_t)(m0 + wrow + c) * KP + g * 8;
  s8b a0[4], a1[4];
  LDA_BS(a0, 0);
  LDA_BS(a1, 1);
  #pragma unroll
  for (int ks = 0; ks < NKS; ++ks) {
    if ((ks & 1) == 0) {
      STEP_BS(a0, ks);
      if (ks + 2 < NKS) LDA_BS(a0, ks + 2);
    } else {
      STEP_BS(a1, ks);
      if (ks + 2 < NKS) LDA_BS(a1, ks + 2);
    }
  }

  float bv[8];
  #pragma unroll
  for (int nf = 0; nf < 8; ++nf) bv[nf] = bias[n0 + nf * 16 + c];
  __syncthreads();   // all B reads done before bounce overwrites LDS
  // epilogue: two 64-col halves via LDS bounce -> coalesced us8 stores
  #pragma unroll
  for (int half = 0; half < 2; ++half) {
    #pragma unroll
    for (int mf = 0; mf < 4; ++mf)
      #pragma unroll
      for (int r = 0; r < 4; ++r) {
        const int row = wrow + mf * 16 + g * 4 + r;
        #pragma unroll
        for (int nf2 = 0; nf2 < 4; ++nf2) {
          const int nf = half * 4 + nf2;
          float v = acc[mf][nf][r] + bv[nf];
          if constexpr (EPI == 0) v = gelu_f(v);
          lds[row * 64 + nf2 * 16 + c] = f2bf(v);
        }
      }
    __syncthreads();
    #pragma unroll
    for (int i = 0; i < 8; ++i) {
      const int f = i * 512 + t;
      const int row = f >> 3, sl = f & 7;
      *(us8*)(out + (size_t)(m0 + row) * OSTR + n0 + half * 64 + sl * 8) =
          *(const us8*)&lds[row * 64 + sl * 8];
    }
    __syncthreads();
  }
}

// ---------- per-pixel mean/rstd over E channels (bf16 input) ----------
__global__ __launch_bounds__(256)
void rowstats(const unsigned short* __restrict__ X, float* __restrict__ mean,
              float* __restrict__ rstd) {
  const int row = blockIdx.x * 4 + (threadIdx.x >> 6);
  const int lane = threadIdx.x & 63;
  const uint2 u = *(const uint2*)(X + (size_t)row * E_ + lane * 4);
  float a = bf2f(u.x & 0xffff), b = bf2f(u.x >> 16);
  float c = bf2f(u.y & 0xffff), d = bf2f(u.y >> 16);
  float s = a + b + c + d;
  float s2 = a * a + b * b + c * c + d * d;
  #pragma unroll
  for (int o = 32; o > 0; o >>= 1) { s += __shfl_down(s, o, 64); s2 += __shfl_down(s2, o, 64); }
  if (lane == 0) {
    const float m = s * (1.0f / E_);
    mean[row] = m;
    rstd[row] = rsqrtf(s2 * (1.0f / E_) - m * m + 1e-5f);
  }
}

// ---------- depthwise 3x3 with on-the-fly LN, 4-row tile, bf16 in/out ----------
__global__ __launch_bounds__(256)
void dwconv_ln2(const unsigned short* __restrict__ X2, const float* __restrict__ mean,
                const float* __restrict__ rstd, const float* __restrict__ g2,
                const float* __restrict__ b2, const float* __restrict__ wgt,
                const float* __restrict__ cbias, unsigned short* __restrict__ out) {
  const int d = threadIdx.x;
  const int w0 = blockIdx.x * 16;
  const int h0 = blockIdx.y * 4;
  const int b = blockIdx.z;
  float wq[9];
  #pragma unroll
  for (int i = 0; i < 9; ++i) wq[i] = wgt[i * E_ + d];
  const float gg = g2[d], bb = b2[d], bias = cbias[d];
  float o[4][16];
  #pragma unroll
  for (int oy = 0; oy < 4; ++oy)
    #pragma unroll
    for (int j = 0; j < 16; ++j) o[oy][j] = bias;
  #pragma unroll
  for (int s = 0; s < 6; ++s) {
    const int hh = h0 - 1 + s;
    if (hh < 0 || hh >= H_) continue;
    const size_t rowb = (size_t)b * HW_ + hh * W_;
    float r[18];
    #pragma unroll
    for (int i = 0; i < 18; ++i) {
      const int ww = w0 + i - 1;
      if (ww >= 0 && ww < W_) {
        const size_t p = rowb + ww;
        const float x = bf2f(X2[p * E_ + d]);
        r[i] = (x - mean[p]) * rstd[p] * gg + bb;
      } else r[i] = 0.f;
    }
    #pragma unroll
    for (int ky = 0; ky < 3; ++ky) {
      const int oy = s - ky;
      if (oy < 0 || oy >= 4) continue;
      const float w_0 = wq[ky * 3], w_1 = wq[ky * 3 + 1], w_2 = wq[ky * 3 + 2];
      #pragma unroll
      for (int j = 0; j < 16; ++j)
        o[oy][j] += r[j] * w_0 + r[j + 1] * w_1 + r[j + 2] * w_2;
    }
  }
  #pragma unroll
  for (int oy = 0; oy < 4; ++oy) {
    const size_t ob_ = (size_t)b * HW_ + (h0 + oy) * W_ + w0;
    #pragma unroll
    for (int j = 0; j < 16; ++j) out[(ob_ + j) * E_ + d] = f2bf(o[oy][j]);
  }
}

// ---------- t_img / t_msk reductions ----------
__global__ __launch_bounds__(256)
void tvec_k(const float* __restrict__ img, const float* __restrict__ msk,
            const float* __restrict__ icw, const float* __restrict__ icb,
            const float* __restrict__ mcw, const float* __restrict__ mcb,
            float* __restrict__ timg, float* __restrict__ tmsk) {
  const int b = blockIdx.y;
  const int lane = threadIdx.x & 63;
  const int p = blockIdx.x * 64 + lane;
  const int seg = threadIdx.x >> 6;
  __shared__ float red[4][64];
  float s = 0.f;
  const float* ib = img + (size_t)b * E_ * HW_ + p;
  #pragma unroll 4
  for (int e = seg * 64; e < seg * 64 + 64; ++e) s += ib[(size_t)e * HW_] * icw[e];
  red[seg][lane] = s;
  __syncthreads();
  if (seg == 0) {
    float tot = red[0][lane] + red[1][lane] + red[2][lane] + red[3][lane] + icb[0];
    timg[(size_t)b * HW_ + p] = tot;
    float s2 = mcb[0];
    const float* mb = msk + (size_t)b * NC_ * HW_ + p;
    #pragma unroll
    for (int c = 0; c < NC_; ++c) s2 += mb[(size_t)c * HW_] * mcw[c];
    tmsk[(size_t)b * HW_ + p] = s2;
  }
}

// ---------- att_image / att_mask: [B,HW] @ [HW,OF] + bias ----------
__global__ __launch_bounds__(256)
void attvec_k(const float* __restrict__ timg, const float* __restrict__ tmsk,
              const float* __restrict__ ipw, const float* __restrict__ ipb,
              const float* __restrict__ mpw, const float* __restrict__ mpb,
              float* __restrict__ ai, float* __restrict__ am) {
  const int b = blockIdx.x;
  const int mat = blockIdx.y;
  const float* tv = mat ? tmsk : timg;
  const float* wp = mat ? mpw : ipw;
  const float* bp = mat ? mpb : ipb;
  float* op = mat ? am : ai;
  const int o = threadIdx.x & 63, seg = threadIdx.x >> 6;
  float s = 0.f;
  for (int p = seg * 1024; p < seg * 1024 + 1024; ++p)
    s += tv[(size_t)b * HW_ + p] * wp[(size_t)p * OF_ + o];
  __shared__ float red[4][64];
  red[seg][o] = s;
  __syncthreads();
  if (seg == 0) op[b * OF_ + o] = red[0][o] + red[1][o] + red[2][o] + red[3][o] + bp[o];
}

// ---------- attbias ----------
__global__ __launch_bounds__(256)
void attbias(const float* __restrict__ ai, const float* __restrict__ am,
             const float* __restrict__ alpha, const float* __restrict__ beta,
             float* __restrict__ A1, float* __restrict__ asd, float* __restrict__ bsd) {
  const int p = blockIdx.x * 256 + threadIdx.x;
  const int b = blockIdx.y;
  const float scl = 0.17677669529663687f;  // 1/sqrt(32)
  A1[(size_t)b * HW_ + p] = ai[b * OF_ + (p >> 6)] * am[b * OF_ + (p & 63)] * alpha[p] * scl;
  if (b == 0) {
    asd[p] = alpha[p] * scl;
    bsd[p] = beta[p] * scl;
  }
}

// ---------- MFMA flash attention partials (k/v from fused kv buffer) ----------
__global__ __launch_bounds__(256)
void attn_mfma(const float* __restrict__ qbuf, const unsigned short* __restrict__ kv,
               const float* __restrict__ masks,
               const float* __restrict__ A1, const float* __restrict__ asd,
               const float* __restrict__ bsd, const float* __restrict__ cw,
               const float* __restrict__ cb,
               float* __restrict__ pacc, float* __restrict__ pm, float* __restrict__ pl) {
  const int ch = blockIdx.x, n = blockIdx.y, b = blockIdx.z;
  const int t = threadIdx.x, wid = t >> 6, lane = t & 63;
  const int c = lane & 15, g = lane >> 4;
  __shared__ __align__(16) unsigned short Pl[4][48 * 88];
  __shared__ __align__(16) unsigned short Vt[4][32 * 72];
  __shared__ __align__(16) float scw[4][64];

  const size_t bhw = (size_t)b * HW_;
  const int koff = n * HD_;
  const int voff = 256 + koff;
  const int pbase = ch * 1024 + wid * 256;

  s8b qf[3];
  float cwq[3], cbq[3];
  int cls[3];
  #pragma unroll
  for (int nt = 0; nt < 3; ++nt) {
    const int q = nt * 16 + c;
    unsigned short tmp[8];
    if (q < Q_) {
      const float* qp = qbuf + ((size_t)b * Q_ + q) * E_ + koff + g * 8;
      const float4 f0 = *(const float4*)qp;
      const float4 f1 = *(const float4*)(qp + 4);
      tmp[0] = f2bf(f0.x); tmp[1] = f2bf(f0.y); tmp[2] = f2bf(f0.z); tmp[3] = f2bf(f0.w);
      tmp[4] = f2bf(f1.x); tmp[5] = f2bf(f1.y); tmp[6] = f2bf(f1.z); tmp[7] = f2bf(f1.w);
      cwq[nt] = cw[q]; cbq[nt] = cb[q];
    } else {
      #pragma unroll
      for (int i = 0; i < 8; ++i) tmp[i] = 0;
      cwq[nt] = 0.f; cbq[nt] = 0.f;
    }
    qf[nt] = *(const s8b*)tmp;
    cls[nt] = min(q / 5, NC_ - 1);
  }

  f32x4 acc_o[3][2];
  #pragma unroll
  for (int qt = 0; qt < 3; ++qt)
    #pragma unroll
    for (int dt = 0; dt < 2; ++dt) acc_o[qt][dt] = (f32x4){0.f, 0.f, 0.f, 0.f};
  float m_r[3] = {-1e30f, -1e30f, -1e30f};
  float l_r[3] = {0.f, 0.f, 0.f};

  for (int tile = 0; tile < 4; ++tile) {
    const int p0 = pbase + tile * 64;
    s8b kf[4];
    #pragma unroll
    for (int mt = 0; mt < 4; ++mt)
      kf[mt] = *(const s8b*)(kv + (bhw + p0 + mt * 16 + c) * KVS_ + koff + g * 8);
    #pragma unroll
    for (int cp = 0; cp < 4; ++cp) {
      const us8 vr = *(const us8*)(kv + (bhw + p0 + lane) * KVS_ + voff + cp * 8);
      #pragma unroll
      for (int i = 0; i < 8; ++i) Vt[wid][(cp * 8 + i) * 72 + lane] = vr[i];
    }
    f32x4 sa[3][4];
    #pragma unroll
    for (int nt = 0; nt < 3; ++nt)
      #pragma unroll
      for (int mt = 0; mt < 4; ++mt)
        sa[nt][mt] = __builtin_amdgcn_mfma_f32_16x16x32_bf16(kf[mt], qf[nt],
                     (f32x4){0.f, 0.f, 0.f, 0.f}, 0, 0, 0);
    f32x4 A1v[4], asv[4], bsv[4];
    #pragma unroll
    for (int mt = 0; mt < 4; ++mt) {
      const int pp = p0 + mt * 16 + g * 4;
      A1v[mt] = *(const f32x4*)(A1 + bhw + pp);
      asv[mt] = *(const f32x4*)(asd + pp);
      bsv[mt] = *(const f32x4*)(bsd + pp);
    }
    #pragma unroll
    for (int nt = 0; nt < 3; ++nt) {
      const float* mrow = masks + ((size_t)b * NC_ + cls[nt]) * HW_;
      f32x4 att[4];
      #pragma unroll
      for (int mt = 0; mt < 4; ++mt) {
        const f32x4 mk = *(const f32x4*)(mrow + p0 + mt * 16 + g * 4);
        att[mt] = A1v[mt] * cwq[nt] + asv[mt] * cbq[nt] + sa[nt][mt] * mk * bsv[mt];
      }
      float mx = -1e30f;
      #pragma unroll
      for (int mt = 0; mt < 4; ++mt)
        mx = fmaxf(mx, fmaxf(fmaxf(att[mt][0], att[mt][1]), fmaxf(att[mt][2], att[mt][3])));
      mx = fmaxf(mx, __shfl_xor(mx, 16));
      mx = fmaxf(mx, __shfl_xor(mx, 32));
      const float newm = fmaxf(m_r[nt], mx);
      const float sc = __expf(m_r[nt] - newm);
      m_r[nt] = newm;
      float sum = 0.f;
      #pragma unroll
      for (int mt = 0; mt < 4; ++mt) {
        #pragma unroll
        for (int i = 0; i < 4; ++i) att[mt][i] = __expf(att[mt][i] - newm);
        sum += (att[mt][0] + att[mt][1]) + (att[mt][2] + att[mt][3]);
      }
      sum += __shfl_xor(sum, 16);
      sum += __shfl_xor(sum, 32);
      l_r[nt] = l_r[nt] * sc + sum;
      if (g == 0) scw[wid][nt * 16 + c] = sc;
      #pragma unroll
      for (int mt = 0; mt < 4; ++mt) {
        uint2 pw;
        pw.x = (unsigned int)f2bf(att[mt][0]) | ((unsigned int)f2bf(att[mt][1]) << 16);
        pw.y = (unsigned int)f2bf(att[mt][2]) | ((unsigned int)f2bf(att[mt][3]) << 16);
        *(uint2*)&Pl[wid][(nt * 16 + c) * 88 + mt * 16 + g * 4] = pw;
      }
    }
    __syncthreads();
    f32x4 sc4[3];
    #pragma unroll
    for (int qt = 0; qt < 3; ++qt) sc4[qt] = *(const f32x4*)&scw[wid][qt * 16 + g * 4];
    #pragma unroll
    for (int qt = 0; qt < 3; ++qt)
      #pragma unroll
      for (int dt = 0; dt < 2; ++dt)
        #pragma unroll
        for (int r = 0; r < 4; ++r) acc_o[qt][dt][r] *= sc4[qt][r];
    #pragma unroll
    for (int ks = 0; ks < 2; ++ks) {
      s8b pf[3], vf[2];
      #pragma unroll
      for (int qt = 0; qt < 3; ++qt)
        pf[qt] = *(const s8b*)&Pl[wid][(qt * 16 + c) * 88 + ks * 32 + g * 8];
      #pragma unroll
      for (int dt = 0; dt < 2; ++dt)
        vf[dt] = *(const s8b*)&Vt[wid][(dt * 16 + c) * 72 + ks * 32 + g * 8];
      #pragma unroll
      for (int qt = 0; qt < 3; ++qt)
        #pragma unroll
        for (int dt = 0; dt < 2; ++dt)
          acc_o[qt][dt] = __builtin_amdgcn_mfma_f32_16x16x32_bf16(pf[qt], vf[dt], acc_o[qt][dt], 0, 0, 0);
    }
    __syncthreads();
  }
  const int pidx = ((b * NH_ + n) * NPART_) + ch * 4 + wid;
  #pragma unroll
  for (int qt = 0; qt < 3; ++qt)
    #pragma unroll
    for (int r = 0; r < 4; ++r) {
      const int q = qt * 16 + g * 4 + r;
      if (q < Q_) {
        #pragma unroll
        for (int dt = 0; dt < 2; ++dt)
          pacc[((size_t)pidx * Q_ + q) * HD_ + dt * 16 + c] = acc_o[qt][dt][r];
      }
    }
  if (g == 0) {
    #pragma unroll
    for (int nt = 0; nt < 3; ++nt) {
      const int q = nt * 16 + c;
      if (q < Q_) {
        pm[(size_t)pidx * Q_ + q] = m_r[nt];
        pl[(size_t)pidx * Q_ + q] = l_r[nt];
      }
    }
  }
}

// ---------- combine partials -> ctx[B,Q,E] ----------
__global__ __launch_bounds__(256)
void attn_comb(const float* __restrict__ pacc, const float* __restrict__ pm,
               const float* __restrict__ pl, float* __restrict__ ctx) {
  const int idx = blockIdx.x * 256 + threadIdx.x;
  const int e = idx & 255;
  const int r = idx >> 8;
  const int q = r % Q_;
  const int b = r / Q_;
  const int n = e >> 5, d = e & 31;
  const int base = (b * NH_ + n) * NPART_;
  float M = -1e30f;
  #pragma unroll
  for (int cc = 0; cc < NPART_; ++cc) M = fmaxf(M, pm[(size_t)(base + cc) * Q_ + q]);
  float L = 0.f, O = 0.f;
  #pragma unroll
  for (int cc = 0; cc < NPART_; ++cc) {
    const size_t o2 = (size_t)(base + cc) * Q_ + q;
    const float w = __expf(pm[o2] - M);
    L += pl[o2] * w;
    O += pacc[o2 * HD_ + d] * w;
  }
  ctx[idx] = O / L;
}

extern "C" void kernel_launch(void* const* d_in, const int* in_sizes, int n_in,
                              void* d_out, int out_size, void* d_ws, size_t ws_size,
                              hipStream_t stream) {
  (void)in_sizes; (void)n_in; (void)out_size; (void)ws_size;
  const float* qp    = (const float*)d_in[0];
  const float* img   = (const float*)d_in[1];
  const float* msk   = (const float*)d_in[2];
  const float* masks = (const float*)d_in[3];
  const float* ln_g  = (const float*)d_in[4];
  const float* ln_b  = (const float*)d_in[5];
  const float* qw    = (const float*)d_in[6];
  const float* qb    = (const float*)d_in[7];
  const float* x1w   = (const float*)d_in[8];
  const float* x1b   = (const float*)d_in[9];
  const float* x2w   = (const float*)d_in[10];
  const float* x2b   = (const float*)d_in[11];
  const float* ln2g  = (const float*)d_in[12];
  const float* ln2b  = (const float*)d_in[13];
  const float* dww   = (const float*)d_in[14];
  const float* dwb   = (const float*)d_in[15];
  const float* kw    = (const float*)d_in[16];
  const float* kb    = (const float*)d_in[17];
  const float* vw    = (const float*)d_in[18];
  const float* vb    = (const float*)d_in[19];
  const float* icw   = (const float*)d_in[20];
  const float* icb   = (const float*)d_in[21];
  const float* mcw   = (const float*)d_in[22];
  const float* mcb   = (const float*)d_in[23];
  const float* ipw   = (const float*)d_in[24];
  const float* ipb   = (const float*)d_in[25];
  const float* mpw   = (const float*)d_in[26];
  const float* mpb   = (const float*)d_in[27];
  const float* cw    = (const float*)d_in[28];
  const float* cb    = (const float*)d_in[29];
  const float* alpha = (const float*)d_in[30];
  const float* beta  = (const float*)d_in[31];
  const float* ow    = (const float*)d_in[32];
  const float* ob    = (const float*)d_in[33];

  char* wsb = (char*)d_ws;
  const size_t MB = 1024 * 1024;
  unsigned short* xcatT = (unsigned short*)(wsb);            // 40MB; reused as xf after x1
  unsigned short* xf    = xcatT;
  unsigned short* x1buf = (unsigned short*)(wsb + 42 * MB);  // 32MB
  unsigned short* x2    = (unsigned short*)(wsb + 76 * MB);  // 32MB; kv overlays after dwconv
  unsigned short* kv    = (unsigned short*)(wsb + 76 * MB);  // 64MB (76..140)
  unsigned short* wt1 = (unsigned short*)(wsb + 141 * MB);   // 256x320
  unsigned short* wt2 = wt1 + 256 * KP1_;                    // 256x256
  unsigned short* wtkv = wt2 + 256 * 256;                    // 512x256
  float* fb    = (float*)(wsb + 143 * MB);
  float* kvbias = fb;                                        // 512
  float* qbuf  = kvbias + 512;
  float* meanb = qbuf + (size_t)B_ * Q_ * E_;
  float* rstdb = meanb + (size_t)B_ * HW_;
  float* timg  = rstdb + (size_t)B_ * HW_;
  float* tmsk  = timg + (size_t)B_ * HW_;
  float* aib   = tmsk + (size_t)B_ * HW_;
  float* amb   = aib + B_ * OF_;
  float* A1b   = amb + B_ * OF_;
  float* asdb  = A1b + (size_t)B_ * HW_;
  float* bsdb  = asdb + HW_;
  float* pacc  = bsdb + HW_;
  float* pmb   = pacc + (size_t)B_ * NH_ * NPART_ * Q_ * HD_;
  float* plb   = pmb + (size_t)B_ * NH_ * NPART_ * Q_;
  float* ctx   = plb + (size_t)B_ * NH_ * NPART_ * Q_;

  // prep
  wprep<<<dim3(KP1_, 4), dim3(256), 0, stream>>>(x1w, x2w, kw, vw, kb, vb, wt1, wt2, wtkv, kvbias);
  xcat_t<<<dim3(64, 5, B_), dim3(256), 0, stream>>>(img, msk, xcatT);
  // q branch
  row_gemm256<true><<<dim3(B_ * Q_), dim3(256), 0, stream>>>(qp, ln_g, ln_b, qw, qb, qbuf);
  // x1 = gelu(xcat @ W1^T + b1)   [B-stationary]
  bsgemm<0, KP1_, 256><<<dim3(128, 2), dim3(512), 0, stream>>>(xcatT, wt1, x1b, x1buf);
  // x2 = x1 @ W2^T + b2           [B-stationary]
  bsgemm<1, 256, 256><<<dim3(128, 2), dim3(512), 0, stream>>>(x1buf, wt2, x2b, x2);
  // channel-LN stats
  rowstats<<<dim3(B_ * HW_ / 4), dim3(256), 0, stream>>>(x2, meanb, rstdb);
  // depthwise 3x3 with fused LN -> xf (overlays xcatT)
  dwconv_ln2<<<dim3(4, 16, B_), dim3(256), 0, stream>>>(x2, meanb, rstdb, ln2g, ln2b, dww, dwb, xf);
  // fused k+v (N=512 via grid.y)  [B-stationary]
  bsgemm<1, 256, KVS_><<<dim3(128, 4), dim3(512), 0, stream>>>(xf, wtkv, kvbias, kv);
  // class-attention bias vectors
  tvec_k<<<dim3(64, B_), dim3(256), 0, stream>>>(img, msk, icw, icb, mcw, mcb, timg, tmsk);
  attvec_k<<<dim3(B_, 2), dim3(256), 0, stream>>>(timg, tmsk, ipw, ipb, mpw, mpb, aib, amb);
  attbias<<<dim3(HW_ / 256, B_), dim3(256), 0, stream>>>(aib, amb, alpha, beta, A1b, asdb, bsdb);
  // attention
  attn_mfma<<<dim3(4, NH_, B_), dim3(256), 0, stream>>>(qbuf, kv, masks, A1b, asdb, bsdb,
                                                        cw, cb, pacc, pmb, plb);
  attn_comb<<<dim3(B_ * Q_ * E_ / 256), dim3(256), 0, stream>>>(pacc, pmb, plb, ctx);
  // final projection
  row_gemm256<false><<<dim3(B_ * Q_), dim3(256), 0, stream>>>(ctx, nullptr, nullptr, ow, ob, (float*)d_out);
}

// Round 10
// 270.940 us; speedup vs baseline: 1.2615x; 1.2615x over previous
//
#include <hip/hip_runtime.h>
#include <math.h>

constexpr int B_ = 16, E_ = 256, NC_ = 8, Q_ = 40, H_ = 64, W_ = 64, HW_ = 4096;
constexpr int NH_ = 8, HD_ = 32, OF_ = 64;
constexpr int KP1_ = 320;          // padded K for gemm1 (E+NC=264 -> 320)
constexpr int NPART_ = 16;         // attention partials per (b,head): 4 chunks x 4 waves
constexpr int KVS_ = 512;          // kv buffer row stride (k cols 0..255, v cols 256..511)

typedef __attribute__((ext_vector_type(8))) unsigned short us8;
typedef __attribute__((ext_vector_type(8))) short s8b;     // bf16 MFMA frag
typedef __attribute__((ext_vector_type(4))) float f32x4;

__device__ __forceinline__ float gelu_f(float x) {
  return 0.5f * x * (1.0f + erff(x * 0.70710678118654752f));
}
__device__ __forceinline__ float bf2f(unsigned short u) {
  return __uint_as_float(((unsigned int)u) << 16);
}
__device__ __forceinline__ unsigned short f2bf(float f) {
  unsigned int u = __float_as_uint(f);
  u = u + 0x7fff + ((u >> 16) & 1);  // RNE
  return (unsigned short)(u >> 16);
}
// async global->LDS 16B; LDS dest linear in lane (wave base + lane*16)
__device__ __forceinline__ void gl_lds16(const unsigned short* g, unsigned short* l) {
  __builtin_amdgcn_global_load_lds(
      (const __attribute__((address_space(1))) unsigned int*)g,
      (__attribute__((address_space(3))) unsigned int*)l, 16, 0, 0);
}

// ---------- q branch (DO_LN=true) / final projection (DO_LN=false) ----------
template<bool DO_LN>
__global__ __launch_bounds__(256)
void row_gemm256(const float* __restrict__ X, const float* __restrict__ g,
                 const float* __restrict__ bt, const float* __restrict__ Wm,
                 const float* __restrict__ bias, float* __restrict__ Y) {
  const int row = blockIdx.x;
  const int t = threadIdx.x;
  __shared__ float xs[E_];
  float x = X[(size_t)row * E_ + t];
  if constexpr (DO_LN) {
    __shared__ float rs[4], rs2[4];
    __shared__ float smean, srstd;
    float s = x, s2 = x * x;
    #pragma unroll
    for (int o = 32; o > 0; o >>= 1) { s += __shfl_down(s, o, 64); s2 += __shfl_down(s2, o, 64); }
    if ((t & 63) == 0) { rs[t >> 6] = s; rs2[t >> 6] = s2; }
    __syncthreads();
    if (t == 0) {
      float S = rs[0] + rs[1] + rs[2] + rs[3];
      float S2 = rs2[0] + rs2[1] + rs2[2] + rs2[3];
      float m = S * (1.0f / E_);
      smean = m;
      srstd = rsqrtf(S2 * (1.0f / E_) - m * m + 1e-5f);
    }
    __syncthreads();
    x = (x - smean) * srstd * g[t] + bt[t];
  }
  xs[t] = x;
  __syncthreads();
  float acc = bias[t];
  #pragma unroll 8
  for (int c = 0; c < E_; ++c) acc += xs[c] * Wm[(size_t)c * E_ + t];
  Y[(size_t)row * E_ + t] = acc;
}

// ---------- weight prep: transpose+cast; kv weights stacked [512][256] ----------
__global__ __launch_bounds__(256)
void wprep(const float* __restrict__ w1, const float* __restrict__ w2,
           const float* __restrict__ wk, const float* __restrict__ wv,
           const float* __restrict__ kb, const float* __restrict__ vb,
           unsigned short* __restrict__ o1, unsigned short* __restrict__ o2,
           unsigned short* __restrict__ okv, float* __restrict__ kvbias) {
  const int n = threadIdx.x;
  const int k = blockIdx.x;
  const int which = blockIdx.y;
  if (which == 0) {
    float v = (k < 264) ? w1[(size_t)k * E_ + n] : 0.f;
    o1[(size_t)n * KP1_ + k] = f2bf(v);
  } else if (k < 256) {
    if (which == 1) {
      o2[(size_t)n * 256 + k] = f2bf(w2[(size_t)k * E_ + n]);
    } else if (which == 2) {
      okv[(size_t)n * 256 + k] = f2bf(wk[(size_t)k * E_ + n]);
      if (k == 0) kvbias[n] = kb[n];
    } else {
      okv[(size_t)(256 + n) * 256 + k] = f2bf(wv[(size_t)k * E_ + n]);
      if (k == 0) kvbias[256 + n] = vb[n];
    }
  }
}

// ---------- xcatT: bf16 [B*HW][KP1] from channel-major img/msk ----------
__global__ __launch_bounds__(256)
void xcat_t(const float* __restrict__ img, const float* __restrict__ msk,
            unsigned short* __restrict__ out) {
  __shared__ float tile[64][65];
  const int t = threadIdx.x;
  const int p0 = blockIdx.x * 64;
  const int k0 = blockIdx.y * 64;
  const int b = blockIdx.z;
  const int kk = t >> 6, pl = t & 63;
  #pragma unroll
  for (int ki = 0; ki < 16; ++ki) {
    const int k = k0 + kk * 16 + ki;
    float v;
    if (k < 256)      v = img[((size_t)b * E_ + k) * HW_ + p0 + pl];
    else if (k < 264) v = msk[((size_t)b * NC_ + (k - 256)) * HW_ + p0 + pl];
    else              v = 0.f;
    tile[pl][kk * 16 + ki] = v;
  }
  __syncthreads();
  const int pr = t >> 2, ch = t & 3;
  unsigned short st[16];
  #pragma unroll
  for (int i = 0; i < 16; ++i) st[i] = f2bf(tile[pr][ch * 16 + i]);
  unsigned short* dst = out + ((size_t)b * HW_ + p0 + pr) * KP1_ + k0 + ch * 16;
  *(us8*)dst = *(const us8*)&st[0];
  *(us8*)(dst + 8) = *(const us8*)&st[8];
}

// ---------- hgemm: m97-style 2-barrier loop, SMALL footprint for block-TLP ----------
// C[M, n0+64 cols] = A[M,KP] @ Wt[n0..n0+64 rows][KP]^T + bias.
// 256 thr (4 waves), tile 128x64, BK=64, single-buffered 24KB LDS, <=128 regs
// -> 4+ blocks/CU resident; independent blocks overlap each other's stage drains.
template<int EPI, int KP, int OSTR>
__global__ __launch_bounds__(256, 4)
void hgemm(const unsigned short* __restrict__ A, const unsigned short* __restrict__ Wt,
           const float* __restrict__ bias, unsigned short* __restrict__ out) {
  constexpr int NT = KP / 64;                     // 4 or 5 K-steps
  __shared__ __align__(16) unsigned short As[128 * 64];  // 16 KB
  __shared__ __align__(16) unsigned short Bs[64 * 64];   // 8 KB
  const int t = threadIdx.x;
  const int m0 = blockIdx.x * 128;
  const int n0 = blockIdx.y * 64;
  const int w = t >> 6, lane = t & 63;
  const int c = lane & 15, g = lane >> 4;
  const int wm = (w & 1) * 64, wn = (w >> 1) * 32;

  f32x4 acc[4][2];
  #pragma unroll
  for (int i = 0; i < 4; ++i)
    #pragma unroll
    for (int j = 0; j < 2; ++j) acc[i][j] = (f32x4){0.f, 0.f, 0.f, 0.f};

  for (int kt = 0; kt < NT; ++kt) {
    if (kt) __syncthreads();            // prior reads done before overwrite
    // stage A tile 128x64 (4 slot-loads/thread), source-XOR-swizzled
    #pragma unroll
    for (int i = 0; i < 4; ++i) {
      const int f = i * 256 + t;
      const int row = f >> 3, s = f & 7;
      gl_lds16(A + (size_t)(m0 + row) * KP + kt * 64 + (s ^ (row & 7)) * 8, As + f * 8);
    }
    // stage B tile 64x64 (2 slot-loads/thread)
    #pragma unroll
    for (int i = 0; i < 2; ++i) {
      const int f = i * 256 + t;
      const int row = f >> 3, s = f & 7;
      gl_lds16(Wt + (size_t)(n0 + row) * KP + kt * 64 + (s ^ (row & 7)) * 8, Bs + f * 8);
    }
    __syncthreads();                    // drains vmcnt -> tiles ready
    #pragma unroll
    for (int ks = 0; ks < 2; ++ks) {
      s8b af[4], bf[2];
      #pragma unroll
      for (int mf = 0; mf < 4; ++mf) {
        const int row = wm + mf * 16 + c;
        af[mf] = *(const s8b*)&As[row * 64 + ((ks * 4 + g) ^ (row & 7)) * 8];
      }
      #pragma unroll
      for (int nf = 0; nf < 2; ++nf) {
        const int row = wn + nf * 16 + c;
        bf[nf] = *(const s8b*)&Bs[row * 64 + ((ks * 4 + g) ^ (row & 7)) * 8];
      }
      #pragma unroll
      for (int mf = 0; mf < 4; ++mf)
        #pragma unroll
        for (int nf = 0; nf < 2; ++nf)
          acc[mf][nf] = __builtin_amdgcn_mfma_f32_16x16x32_bf16(af[mf], bf[nf], acc[mf][nf], 0, 0, 0);
    }
  }

  float bv[2];
  #pragma unroll
  for (int nf = 0; nf < 2; ++nf) bv[nf] = bias[n0 + wn + nf * 16 + c];
  __syncthreads();                      // compute reads done; reuse As as bounce
  #pragma unroll
  for (int mf = 0; mf < 4; ++mf)
    #pragma unroll
    for (int r = 0; r < 4; ++r) {
      const int row = wm + mf * 16 + g * 4 + r;
      #pragma unroll
      for (int nf = 0; nf < 2; ++nf) {
        float v = acc[mf][nf][r] + bv[nf];
        if constexpr (EPI == 0) v = gelu_f(v);
        As[row * 64 + wn + nf * 16 + c] = f2bf(v);
      }
    }
  __syncthreads();
  #pragma unroll
  for (int i = 0; i < 4; ++i) {         // coalesced 16B stores
    const int f = i * 256 + t;
    const int row = f >> 3, sl = f & 7;
    *(us8*)(out + (size_t)(m0 + row) * OSTR + n0 + sl * 8) = *(const us8*)&As[row * 64 + sl * 8];
  }
}

// ---------- per-pixel mean/rstd over E channels (bf16 input) ----------
__global__ __launch_bounds__(256)
void rowstats(const unsigned short* __restrict__ X, float* __restrict__ mean,
              float* __restrict__ rstd) {
  const int row = blockIdx.x * 4 + (threadIdx.x >> 6);
  const int lane = threadIdx.x & 63;
  const uint2 u = *(const uint2*)(X + (size_t)row * E_ + lane * 4);
  float a = bf2f(u.x & 0xffff), b = bf2f(u.x >> 16);
  float c = bf2f(u.y & 0xffff), d = bf2f(u.y >> 16);
  float s = a + b + c + d;
  float s2 = a * a + b * b + c * c + d * d;
  #pragma unroll
  for (int o = 32; o > 0; o >>= 1) { s += __shfl_down(s, o, 64); s2 += __shfl_down(s2, o, 64); }
  if (lane == 0) {
    const float m = s * (1.0f / E_);
    mean[row] = m;
    rstd[row] = rsqrtf(s2 * (1.0f / E_) - m * m + 1e-5f);
  }
}

// ---------- depthwise 3x3 with on-the-fly LN, 4-row tile, bf16 in/out ----------
__global__ __launch_bounds__(256)
void dwconv_ln2(const unsigned short* __restrict__ X2, const float* __restrict__ mean,
                const float* __restrict__ rstd, const float* __restrict__ g2,
                const float* __restrict__ b2, const float* __restrict__ wgt,
                const float* __restrict__ cbias, unsigned short* __restrict__ out) {
  const int d = threadIdx.x;
  const int w0 = blockIdx.x * 16;
  const int h0 = blockIdx.y * 4;
  const int b = blockIdx.z;
  float wq[9];
  #pragma unroll
  for (int i = 0; i < 9; ++i) wq[i] = wgt[i * E_ + d];
  const float gg = g2[d], bb = b2[d], bias = cbias[d];
  float o[4][16];
  #pragma unroll
  for (int oy = 0; oy < 4; ++oy)
    #pragma unroll
    for (int j = 0; j < 16; ++j) o[oy][j] = bias;
  #pragma unroll
  for (int s = 0; s < 6; ++s) {
    const int hh = h0 - 1 + s;
    if (hh < 0 || hh >= H_) continue;
    const size_t rowb = (size_t)b * HW_ + hh * W_;
    float r[18];
    #pragma unroll
    for (int i = 0; i < 18; ++i) {
      const int ww = w0 + i - 1;
      if (ww >= 0 && ww < W_) {
        const size_t p = rowb + ww;
        const float x = bf2f(X2[p * E_ + d]);
        r[i] = (x - mean[p]) * rstd[p] * gg + bb;
      } else r[i] = 0.f;
    }
    #pragma unroll
    for (int ky = 0; ky < 3; ++ky) {
      const int oy = s - ky;
      if (oy < 0 || oy >= 4) continue;
      const float w_0 = wq[ky * 3], w_1 = wq[ky * 3 + 1], w_2 = wq[ky * 3 + 2];
      #pragma unroll
      for (int j = 0; j < 16; ++j)
        o[oy][j] += r[j] * w_0 + r[j + 1] * w_1 + r[j + 2] * w_2;
    }
  }
  #pragma unroll
  for (int oy = 0; oy < 4; ++oy) {
    const size_t ob_ = (size_t)b * HW_ + (h0 + oy) * W_ + w0;
    #pragma unroll
    for (int j = 0; j < 16; ++j) out[(ob_ + j) * E_ + d] = f2bf(o[oy][j]);
  }
}

// ---------- t_img / t_msk reductions ----------
__global__ __launch_bounds__(256)
void tvec_k(const float* __restrict__ img, const float* __restrict__ msk,
            const float* __restrict__ icw, const float* __restrict__ icb,
            const float* __restrict__ mcw, const float* __restrict__ mcb,
            float* __restrict__ timg, float* __restrict__ tmsk) {
  const int b = blockIdx.y;
  const int lane = threadIdx.x & 63;
  const int p = blockIdx.x * 64 + lane;
  const int seg = threadIdx.x >> 6;
  __shared__ float red[4][64];
  float s = 0.f;
  const float* ib = img + (size_t)b * E_ * HW_ + p;
  #pragma unroll 4
  for (int e = seg * 64; e < seg * 64 + 64; ++e) s += ib[(size_t)e * HW_] * icw[e];
  red[seg][lane] = s;
  __syncthreads();
  if (seg == 0) {
    float tot = red[0][lane] + red[1][lane] + red[2][lane] + red[3][lane] + icb[0];
    timg[(size_t)b * HW_ + p] = tot;
    float s2 = mcb[0];
    const float* mb = msk + (size_t)b * NC_ * HW_ + p;
    #pragma unroll
    for (int c = 0; c < NC_; ++c) s2 += mb[(size_t)c * HW_] * mcw[c];
    tmsk[(size_t)b * HW_ + p] = s2;
  }
}

// ---------- att_image / att_mask: [B,HW] @ [HW,OF] + bias ----------
__global__ __launch_bounds__(256)
void attvec_k(const float* __restrict__ timg, const float* __restrict__ tmsk,
              const float* __restrict__ ipw, const float* __restrict__ ipb,
              const float* __restrict__ mpw, const float* __restrict__ mpb,
              float* __restrict__ ai, float* __restrict__ am) {
  const int b = blockIdx.x;
  const int mat = blockIdx.y;
  const float* tv = mat ? tmsk : timg;
  const float* wp = mat ? mpw : ipw;
  const float* bp = mat ? mpb : ipb;
  float* op = mat ? am : ai;
  const int o = threadIdx.x & 63, seg = threadIdx.x >> 6;
  float s = 0.f;
  for (int p = seg * 1024; p < seg * 1024 + 1024; ++p)
    s += tv[(size_t)b * HW_ + p] * wp[(size_t)p * OF_ + o];
  __shared__ float red[4][64];
  red[seg][o] = s;
  __syncthreads();
  if (seg == 0) op[b * OF_ + o] = red[0][o] + red[1][o] + red[2][o] + red[3][o] + bp[o];
}

// ---------- attbias ----------
__global__ __launch_bounds__(256)
void attbias(const float* __restrict__ ai, const float* __restrict__ am,
             const float* __restrict__ alpha, const float* __restrict__ beta,
             float* __restrict__ A1, float* __restrict__ asd, float* __restrict__ bsd) {
  const int p = blockIdx.x * 256 + threadIdx.x;
  const int b = blockIdx.y;
  const float scl = 0.17677669529663687f;  // 1/sqrt(32)
  A1[(size_t)b * HW_ + p] = ai[b * OF_ + (p >> 6)] * am[b * OF_ + (p & 63)] * alpha[p] * scl;
  if (b == 0) {
    asd[p] = alpha[p] * scl;
    bsd[p] = beta[p] * scl;
  }
}

// ---------- MFMA flash attention partials (k/v from fused kv buffer) ----------
__global__ __launch_bounds__(256)
void attn_mfma(const float* __restrict__ qbuf, const unsigned short* __restrict__ kv,
               const float* __restrict__ masks,
               const float* __restrict__ A1, const float* __restrict__ asd,
               const float* __restrict__ bsd, const float* __restrict__ cw,
               const float* __restrict__ cb,
               float* __restrict__ pacc, float* __restrict__ pm, float* __restrict__ pl) {
  const int ch = blockIdx.x, n = blockIdx.y, b = blockIdx.z;
  const int t = threadIdx.x, wid = t >> 6, lane = t & 63;
  const int c = lane & 15, g = lane >> 4;
  __shared__ __align__(16) unsigned short Pl[4][48 * 88];
  __shared__ __align__(16) unsigned short Vt[4][32 * 72];
  __shared__ __align__(16) float scw[4][64];

  const size_t bhw = (size_t)b * HW_;
  const int koff = n * HD_;
  const int voff = 256 + koff;
  const int pbase = ch * 1024 + wid * 256;

  s8b qf[3];
  float cwq[3], cbq[3];
  int cls[3];
  #pragma unroll
  for (int nt = 0; nt < 3; ++nt) {
    const int q = nt * 16 + c;
    unsigned short tmp[8];
    if (q < Q_) {
      const float* qp = qbuf + ((size_t)b * Q_ + q) * E_ + koff + g * 8;
      const float4 f0 = *(const float4*)qp;
      const float4 f1 = *(const float4*)(qp + 4);
      tmp[0] = f2bf(f0.x); tmp[1] = f2bf(f0.y); tmp[2] = f2bf(f0.z); tmp[3] = f2bf(f0.w);
      tmp[4] = f2bf(f1.x); tmp[5] = f2bf(f1.y); tmp[6] = f2bf(f1.z); tmp[7] = f2bf(f1.w);
      cwq[nt] = cw[q]; cbq[nt] = cb[q];
    } else {
      #pragma unroll
      for (int i = 0; i < 8; ++i) tmp[i] = 0;
      cwq[nt] = 0.f; cbq[nt] = 0.f;
    }
    qf[nt] = *(const s8b*)tmp;
    cls[nt] = min(q / 5, NC_ - 1);
  }

  f32x4 acc_o[3][2];
  #pragma unroll
  for (int qt = 0; qt < 3; ++qt)
    #pragma unroll
    for (int dt = 0; dt < 2; ++dt) acc_o[qt][dt] = (f32x4){0.f, 0.f, 0.f, 0.f};
  float m_r[3] = {-1e30f, -1e30f, -1e30f};
  float l_r[3] = {0.f, 0.f, 0.f};

  for (int tile = 0; tile < 4; ++tile) {
    const int p0 = pbase + tile * 64;
    s8b kf[4];
    #pragma unroll
    for (int mt = 0; mt < 4; ++mt)
      kf[mt] = *(const s8b*)(kv + (bhw + p0 + mt * 16 + c) * KVS_ + koff + g * 8);
    #pragma unroll
    for (int cp = 0; cp < 4; ++cp) {
      const us8 vr = *(const us8*)(kv + (bhw + p0 + lane) * KVS_ + voff + cp * 8);
      #pragma unroll
      for (int i = 0; i < 8; ++i) Vt[wid][(cp * 8 + i) * 72 + lane] = vr[i];
    }
    f32x4 sa[3][4];
    #pragma unroll
    for (int nt = 0; nt < 3; ++nt)
      #pragma unroll
      for (int mt = 0; mt < 4; ++mt)
        sa[nt][mt] = __builtin_amdgcn_mfma_f32_16x16x32_bf16(kf[mt], qf[nt],
                     (f32x4){0.f, 0.f, 0.f, 0.f}, 0, 0, 0);
    f32x4 A1v[4], asv[4], bsv[4];
    #pragma unroll
    for (int mt = 0; mt < 4; ++mt) {
      const int pp = p0 + mt * 16 + g * 4;
      A1v[mt] = *(const f32x4*)(A1 + bhw + pp);
      asv[mt] = *(const f32x4*)(asd + pp);
      bsv[mt] = *(const f32x4*)(bsd + pp);
    }
    #pragma unroll
    for (int nt = 0; nt < 3; ++nt) {
      const float* mrow = masks + ((size_t)b * NC_ + cls[nt]) * HW_;
      f32x4 att[4];
      #pragma unroll
      for (int mt = 0; mt < 4; ++mt) {
        const f32x4 mk = *(const f32x4*)(mrow + p0 + mt * 16 + g * 4);
        att[mt] = A1v[mt] * cwq[nt] + asv[mt] * cbq[nt] + sa[nt][mt] * mk * bsv[mt];
      }
      float mx = -1e30f;
      #pragma unroll
      for (int mt = 0; mt < 4; ++mt)
        mx = fmaxf(mx, fmaxf(fmaxf(att[mt][0], att[mt][1]), fmaxf(att[mt][2], att[mt][3])));
      mx = fmaxf(mx, __shfl_xor(mx, 16));
      mx = fmaxf(mx, __shfl_xor(mx, 32));
      const float newm = fmaxf(m_r[nt], mx);
      const float sc = __expf(m_r[nt] - newm);
      m_r[nt] = newm;
      float sum = 0.f;
      #pragma unroll
      for (int mt = 0; mt < 4; ++mt) {
        #pragma unroll
        for (int i = 0; i < 4; ++i) att[mt][i] = __expf(att[mt][i] - newm);
        sum += (att[mt][0] + att[mt][1]) + (att[mt][2] + att[mt][3]);
      }
      sum += __shfl_xor(sum, 16);
      sum += __shfl_xor(sum, 32);
      l_r[nt] = l_r[nt] * sc + sum;
      if (g == 0) scw[wid][nt * 16 + c] = sc;
      #pragma unroll
      for (int mt = 0; mt < 4; ++mt) {
        uint2 pw;
        pw.x = (unsigned int)f2bf(att[mt][0]) | ((unsigned int)f2bf(att[mt][1]) << 16);
        pw.y = (unsigned int)f2bf(att[mt][2]) | ((unsigned int)f2bf(att[mt][3]) << 16);
        *(uint2*)&Pl[wid][(nt * 16 + c) * 88 + mt * 16 + g * 4] = pw;
      }
    }
    __syncthreads();
    f32x4 sc4[3];
    #pragma unroll
    for (int qt = 0; qt < 3; ++qt) sc4[qt] = *(const f32x4*)&scw[wid][qt * 16 + g * 4];
    #pragma unroll
    for (int qt = 0; qt < 3; ++qt)
      #pragma unroll
      for (int dt = 0; dt < 2; ++dt)
        #pragma unroll
        for (int r = 0; r < 4; ++r) acc_o[qt][dt][r] *= sc4[qt][r];
    #pragma unroll
    for (int ks = 0; ks < 2; ++ks) {
      s8b pf[3], vf[2];
      #pragma unroll
      for (int qt = 0; qt < 3; ++qt)
        pf[qt] = *(const s8b*)&Pl[wid][(qt * 16 + c) * 88 + ks * 32 + g * 8];
      #pragma unroll
      for (int dt = 0; dt < 2; ++dt)
        vf[dt] = *(const s8b*)&Vt[wid][(dt * 16 + c) * 72 + ks * 32 + g * 8];
      #pragma unroll
      for (int qt = 0; qt < 3; ++qt)
        #pragma unroll
        for (int dt = 0; dt < 2; ++dt)
          acc_o[qt][dt] = __builtin_amdgcn_mfma_f32_16x16x32_bf16(pf[qt], vf[dt], acc_o[qt][dt], 0, 0, 0);
    }
    __syncthreads();
  }
  const int pidx = ((b * NH_ + n) * NPART_) + ch * 4 + wid;
  #pragma unroll
  for (int qt = 0; qt < 3; ++qt)
    #pragma unroll
    for (int r = 0; r < 4; ++r) {
      const int q = qt * 16 + g * 4 + r;
      if (q < Q_) {
        #pragma unroll
        for (int dt = 0; dt < 2; ++dt)
          pacc[((size_t)pidx * Q_ + q) * HD_ + dt * 16 + c] = acc_o[qt][dt][r];
      }
    }
  if (g == 0) {
    #pragma unroll
    for (int nt = 0; nt < 3; ++nt) {
      const int q = nt * 16 + c;
      if (q < Q_) {
        pm[(size_t)pidx * Q_ + q] = m_r[nt];
        pl[(size_t)pidx * Q_ + q] = l_r[nt];
      }
    }
  }
}

// ---------- combine partials -> ctx[B,Q,E] ----------
__global__ __launch_bounds__(256)
void attn_comb(const float* __restrict__ pacc, const float* __restrict__ pm,
               const float* __restrict__ pl, float* __restrict__ ctx) {
  const int idx = blockIdx.x * 256 + threadIdx.x;
  const int e = idx & 255;
  const int r = idx >> 8;
  const int q = r % Q_;
  const int b = r / Q_;
  const int n = e >> 5, d = e & 31;
  const int base = (b * NH_ + n) * NPART_;
  float M = -1e30f;
  #pragma unroll
  for (int cc = 0; cc < NPART_; ++cc) M = fmaxf(M, pm[(size_t)(base + cc) * Q_ + q]);
  float L = 0.f, O = 0.f;
  #pragma unroll
  for (int cc = 0; cc < NPART_; ++cc) {
    const size_t o2 = (size_t)(base + cc) * Q_ + q;
    const float w = __expf(pm[o2] - M);
    L += pl[o2] * w;
    O += pacc[o2 * HD_ + d] * w;
  }
  ctx[idx] = O / L;
}

extern "C" void kernel_launch(void* const* d_in, const int* in_sizes, int n_in,
                              void* d_out, int out_size, void* d_ws, size_t ws_size,
                              hipStream_t stream) {
  (void)in_sizes; (void)n_in; (void)out_size; (void)ws_size;
  const float* qp    = (const float*)d_in[0];
  const float* img   = (const float*)d_in[1];
  const float* msk   = (const float*)d_in[2];
  const float* masks = (const float*)d_in[3];
  const float* ln_g  = (const float*)d_in[4];
  const float* ln_b  = (const float*)d_in[5];
  const float* qw    = (const float*)d_in[6];
  const float* qb    = (const float*)d_in[7];
  const float* x1w   = (const float*)d_in[8];
  const float* x1b   = (const float*)d_in[9];
  const float* x2w   = (const float*)d_in[10];
  const float* x2b   = (const float*)d_in[11];
  const float* ln2g  = (const float*)d_in[12];
  const float* ln2b  = (const float*)d_in[13];
  const float* dww   = (const float*)d_in[14];
  const float* dwb   = (const float*)d_in[15];
  const float* kw    = (const float*)d_in[16];
  const float* kb    = (const float*)d_in[17];
  const float* vw    = (const float*)d_in[18];
  const float* vb    = (const float*)d_in[19];
  const float* icw   = (const float*)d_in[20];
  const float* icb   = (const float*)d_in[21];
  const float* mcw   = (const float*)d_in[22];
  const float* mcb   = (const float*)d_in[23];
  const float* ipw   = (const float*)d_in[24];
  const float* ipb   = (const float*)d_in[25];
  const float* mpw   = (const float*)d_in[26];
  const float* mpb   = (const float*)d_in[27];
  const float* cw    = (const float*)d_in[28];
  const float* cb    = (const float*)d_in[29];
  const float* alpha = (const float*)d_in[30];
  const float* beta  = (const float*)d_in[31];
  const float* ow    = (const float*)d_in[32];
  const float* ob    = (const float*)d_in[33];

  char* wsb = (char*)d_ws;
  const size_t MB = 1024 * 1024;
  unsigned short* xcatT = (unsigned short*)(wsb);            // 40MB; reused as xf after x1
  unsigned short* xf    = xcatT;
  unsigned short* x1buf = (unsigned short*)(wsb + 42 * MB);  // 32MB
  unsigned short* x2    = (unsigned short*)(wsb + 76 * MB);  // 32MB; kv overlays after dwconv
  unsigned short* kv    = (unsigned short*)(wsb + 76 * MB);  // 64MB (76..140)
  unsigned short* wt1 = (unsigned short*)(wsb + 141 * MB);   // 256x320
  unsigned short* wt2 = wt1 + 256 * KP1_;                    // 256x256
  unsigned short* wtkv = wt2 + 256 * 256;                    // 512x256
  float* fb    = (float*)(wsb + 143 * MB);
  float* kvbias = fb;                                        // 512
  float* qbuf  = kvbias + 512;
  float* meanb = qbuf + (size_t)B_ * Q_ * E_;
  float* rstdb = meanb + (size_t)B_ * HW_;
  float* timg  = rstdb + (size_t)B_ * HW_;
  float* tmsk  = timg + (size_t)B_ * HW_;
  float* aib   = tmsk + (size_t)B_ * HW_;
  float* amb   = aib + B_ * OF_;
  float* A1b   = amb + B_ * OF_;
  float* asdb  = A1b + (size_t)B_ * HW_;
  float* bsdb  = asdb + HW_;
  float* pacc  = bsdb + HW_;
  float* pmb   = pacc + (size_t)B_ * NH_ * NPART_ * Q_ * HD_;
  float* plb   = pmb + (size_t)B_ * NH_ * NPART_ * Q_;
  float* ctx   = plb + (size_t)B_ * NH_ * NPART_ * Q_;

  // prep
  wprep<<<dim3(KP1_, 4), dim3(256), 0, stream>>>(x1w, x2w, kw, vw, kb, vb, wt1, wt2, wtkv, kvbias);
  xcat_t<<<dim3(64, 5, B_), dim3(256), 0, stream>>>(img, msk, xcatT);
  // q branch
  row_gemm256<true><<<dim3(B_ * Q_), dim3(256), 0, stream>>>(qp, ln_g, ln_b, qw, qb, qbuf);
  // x1 = gelu(xcat @ W1^T + b1)
  hgemm<0, KP1_, 256><<<dim3(512, 4), dim3(256), 0, stream>>>(xcatT, wt1, x1b, x1buf);
  // x2 = x1 @ W2^T + b2
  hgemm<1, 256, 256><<<dim3(512, 4), dim3(256), 0, stream>>>(x1buf, wt2, x2b, x2);
  // channel-LN stats
  rowstats<<<dim3(B_ * HW_ / 4), dim3(256), 0, stream>>>(x2, meanb, rstdb);
  // depthwise 3x3 with fused LN -> xf (overlays xcatT)
  dwconv_ln2<<<dim3(4, 16, B_), dim3(256), 0, stream>>>(x2, meanb, rstdb, ln2g, ln2b, dww, dwb, xf);
  // fused k+v (N=512 via grid.y)
  hgemm<1, 256, KVS_><<<dim3(512, 8), dim3(256), 0, stream>>>(xf, wtkv, kvbias, kv);
  // class-attention bias vectors
  tvec_k<<<dim3(64, B_), dim3(256), 0, stream>>>(img, msk, icw, icb, mcw, mcb, timg, tmsk);
  attvec_k<<<dim3(B_, 2), dim3(256), 0, stream>>>(timg, tmsk, ipw, ipb, mpw, mpb, aib, amb);
  attbias<<<dim3(HW_ / 256, B_), dim3(256), 0, stream>>>(aib, amb, alpha, beta, A1b, asdb, bsdb);
  // attention
  attn_mfma<<<dim3(4, NH_, B_), dim3(256), 0, stream>>>(qbuf, kv, masks, A1b, asdb, bsdb,
                                                        cw, cb, pacc, pmb, plb);
  attn_comb<<<dim3(B_ * Q_ * E_ / 256), dim3(256), 0, stream>>>(pacc, pmb, plb, ctx);
  // final projection
  row_gemm256<false><<<dim3(B_ * Q_), dim3(256), 0, stream>>>(ctx, nullptr, nullptr, ow, ob, (float*)d_out);
}